// Round 5
// baseline (1675.959 us; speedup 1.0000x reference)
//
#include <hip/hip_runtime.h>
#include <math.h>

// ---------------------------------------------------------------------------
// KmeansVectorQuantizer forward, MI355X fp32 implementation.
//
// Pipeline:
//   k_prep  : per-codeword tables  U[g][k][d] = sum_c codex[g,k,c]*lnw[c']*pw[d,c']
//             + WL[d] = sum_c lnw*pw, CC[d] = sum_c lnb*pw + pb
//             + s[gk] = sum codex, q[gk] = sum codex^2 (q == cnorm2)
//   k_conv  : grouped 1x1 conv as fp32 VALU GEMM (128x128 tile, 8x8 micro),
//             fused fp64 GroupNorm sum/sumsq atomics per (b,g)
//   k_stats : finalize mean/rstd per (b,g)
//   k_dist  : normalize Ze -> Zn on the fly, fp32 GEMM vs codex (64 tok x 320
//             codes, 8x10 micro), faithful dist = fl(zn2+cn2) - fl(2*dot),
//             argmin (first-index ties), writes probs one-hot, idx, loss atomic
//   k_out   : out[n] = r*(U0[i0]+U1[i1]) - r*m*WL + CC   (table-based LN+Linear)
//
// ws map (bytes):
//   Ze      float[65536*512]   134,217,728
//   U       float[640*1024]      2,621,440
//   WL,CC   float[1024] each         8,192
//   s,q     float[640] each          5,120
//   stats   double[32*2]              512
//   mean,rstd float[32] each          256
//   idx     int[65536*2]          524,288
//   total ~137.4 MB
// ---------------------------------------------------------------------------

#define B_   16
#define T_   4096
#define D_   1024
#define G_   2
#define Cg_  256
#define Dc_  512
#define K_   320
#define N_   (B_*T_)            // 65536 tokens
#define GNM  ((double)(T_*Cg_)) // elements per (b,g) group-norm
#define EPS_GN 1e-5f
#define EPS_LN 1e-5f

// ---------------------------------------------------------------- k_prep ----
__global__ __launch_bounds__(256) void k_prep(
    const float* __restrict__ codex, const float* __restrict__ lnw,
    const float* __restrict__ lnb,   const float* __restrict__ pw,
    const float* __restrict__ pb,
    float* __restrict__ U, float* __restrict__ WL, float* __restrict__ CC,
    float* __restrict__ sArr, float* __restrict__ qArr)
{
  __shared__ float arow[512];
  __shared__ float reds[8];
  const int blk = blockIdx.x;
  const int t = threadIdx.x;
  const int lane = t & 63, wave = t >> 6;

  if (blk < G_ * K_) {
    const int g = blk / K_;
    // stage arow[c] = codex[g][k][c] * lnw[g*256+c]; reduce s, q
    float cv = codex[(size_t)blk * Cg_ + t];
    float lw = lnw[g * Cg_ + t];
    arow[t] = cv * lw;
    float s = cv, q = cv * cv;
    #pragma unroll
    for (int off = 32; off; off >>= 1) {
      s += __shfl_down(s, off);
      q += __shfl_down(q, off);
    }
    if (lane == 0) { reds[wave] = s; reds[4 + wave] = q; }
    __syncthreads();
    if (t == 0) {
      sArr[blk] = reds[0] + reds[1] + reds[2] + reds[3];
      qArr[blk] = reds[4] + reds[5] + reds[6] + reds[7];
    }
    // U rows: one wave per output row d
    const float* pwg = pw + g * Cg_;
    for (int r = wave; r < D_; r += 4) {
      float4 pv = *(const float4*)&pwg[(size_t)r * Dc_ + lane * 4];
      float4 av = *(const float4*)&arow[lane * 4];
      float dot = pv.x*av.x + pv.y*av.y + pv.z*av.z + pv.w*av.w;
      #pragma unroll
      for (int off = 32; off; off >>= 1) dot += __shfl_down(dot, off);
      if (lane == 0) U[(size_t)blk * D_ + r] = dot;
    }
  } else {
    const bool isCC = (blk == G_ * K_ + 1);
    const float* src = isCC ? lnb : lnw;
    arow[t] = src[t];
    arow[256 + t] = src[256 + t];
    __syncthreads();
    for (int r = wave; r < D_; r += 4) {
      const float* prow = &pw[(size_t)r * Dc_];
      float4 p0 = *(const float4*)&prow[lane * 4];
      float4 p1 = *(const float4*)&prow[256 + lane * 4];
      float4 a0 = *(const float4*)&arow[lane * 4];
      float4 a1 = *(const float4*)&arow[256 + lane * 4];
      float dot = p0.x*a0.x + p0.y*a0.y + p0.z*a0.z + p0.w*a0.w
                + p1.x*a1.x + p1.y*a1.y + p1.z*a1.z + p1.w*a1.w;
      #pragma unroll
      for (int off = 32; off; off >>= 1) dot += __shfl_down(dot, off);
      if (lane == 0) {
        if (isCC) CC[r] = dot + pb[r]; else WL[r] = dot;
      }
    }
  }
}

// ---------------------------------------------------------------- k_conv ----
// C[m, n] = sum_k Z[m, g*512+k] * W[g, n, k]   (m: token, n: out-channel)
// Tile 128x128, BK=32, 256 threads, 8x8 micro-tile (rows {4ty..}+{64+4ty..}).
__global__ __launch_bounds__(256, 2) void k_conv(
    const float* __restrict__ Z, const float* __restrict__ W,
    float* __restrict__ Ze, double* __restrict__ statsSum)
{
  const int m0 = blockIdx.x * 128;
  const int n0 = blockIdx.y * 128;
  const int g  = blockIdx.z;
  const int t  = threadIdx.x;
  const int tx = t & 15, ty = t >> 4;
  const int lane = t & 63, wave = t >> 6;

  __shared__ float As[32][132];  // [k][m], stride 132 (16B aligned, bank-safe)
  __shared__ float Bs[32][132];  // [k][n]
  __shared__ double redC[8];

  float acc[8][8];
  #pragma unroll
  for (int i = 0; i < 8; ++i)
    #pragma unroll
    for (int j = 0; j < 8; ++j) acc[i][j] = 0.f;

  const float* Ag = Z + (size_t)m0 * D_ + g * 512;
  const float* Bg = W + ((size_t)g * Cg_ + n0) * 512;

  for (int k0 = 0; k0 < 512; k0 += 32) {
    #pragma unroll
    for (int i = 0; i < 4; ++i) {
      int f = t + 256 * i;          // 0..1023
      int row = f >> 3, cq = f & 7; // row 0..127, 8 float4 per row of 32 k
      float4 a = *(const float4*)&Ag[(size_t)row * D_ + k0 + cq * 4];
      int kk = cq * 4;
      As[kk+0][row] = a.x; As[kk+1][row] = a.y;
      As[kk+2][row] = a.z; As[kk+3][row] = a.w;
      float4 b = *(const float4*)&Bg[(size_t)row * 512 + k0 + cq * 4];
      Bs[kk+0][row] = b.x; Bs[kk+1][row] = b.y;
      Bs[kk+2][row] = b.z; Bs[kk+3][row] = b.w;
    }
    __syncthreads();
    #pragma unroll 8
    for (int kk = 0; kk < 32; ++kk) {
      float av[8], bv[8];
      *(float4*)&av[0] = *(const float4*)&As[kk][ty * 4];
      *(float4*)&av[4] = *(const float4*)&As[kk][64 + ty * 4];
      *(float4*)&bv[0] = *(const float4*)&Bs[kk][tx * 4];
      *(float4*)&bv[4] = *(const float4*)&Bs[kk][64 + tx * 4];
      #pragma unroll
      for (int i = 0; i < 8; ++i)
        #pragma unroll
        for (int j = 0; j < 8; ++j)
          acc[i][j] = fmaf(av[i], bv[j], acc[i][j]);
    }
    __syncthreads();
  }

  // write C + fused GroupNorm partial sums (fp64)
  double bs = 0.0, bq = 0.0;
  #pragma unroll
  for (int i = 0; i < 8; ++i) {
    int m = m0 + ((i < 4) ? (ty * 4 + i) : (64 + ty * 4 + (i - 4)));
    float4 c0, c1;
    c0.x = acc[i][0]; c0.y = acc[i][1]; c0.z = acc[i][2]; c0.w = acc[i][3];
    c1.x = acc[i][4]; c1.y = acc[i][5]; c1.z = acc[i][6]; c1.w = acc[i][7];
    *(float4*)&Ze[(size_t)m * Dc_ + g * Cg_ + n0 + tx * 4] = c0;
    *(float4*)&Ze[(size_t)m * Dc_ + g * Cg_ + n0 + 64 + tx * 4] = c1;
    #pragma unroll
    for (int j = 0; j < 8; ++j) {
      double v = (double)acc[i][j];
      bs += v; bq += v * v;
    }
  }
  #pragma unroll
  for (int off = 32; off; off >>= 1) {
    bs += __shfl_down(bs, off);
    bq += __shfl_down(bq, off);
  }
  if (lane == 0) { redC[wave] = bs; redC[4 + wave] = bq; }
  __syncthreads();
  if (t == 0) {
    const int b = m0 / T_;
    atomicAdd(&statsSum[(b * G_ + g) * 2 + 0], redC[0]+redC[1]+redC[2]+redC[3]);
    atomicAdd(&statsSum[(b * G_ + g) * 2 + 1], redC[4]+redC[5]+redC[6]+redC[7]);
  }
}

// --------------------------------------------------------------- k_stats ----
__global__ void k_stats(const double* __restrict__ statsSum,
                        float* __restrict__ meanArr, float* __restrict__ rstdArr)
{
  int i = threadIdx.x;
  if (i < B_ * G_) {
    double s = statsSum[i * 2 + 0], q = statsSum[i * 2 + 1];
    double mean = s / GNM;
    double var = q / GNM - mean * mean;
    meanArr[i] = (float)mean;
    rstdArr[i] = (float)(1.0 / sqrt(var + (double)EPS_GN));
  }
}

// ---------------------------------------------------------------- k_dist ----
// Per (64-token block, g): Zn staged fully in LDS (normalized), loop codex in
// 32-channel slices; 8 tok x 10 code micro-tile per thread (codes tx+32j).
__global__ __launch_bounds__(256) void k_dist(
    const float* __restrict__ Ze, const float* __restrict__ codex,
    const float* __restrict__ gnw, const float* __restrict__ gnb,
    const float* __restrict__ meanArr, const float* __restrict__ rstdArr,
    const float* __restrict__ qArr, float* __restrict__ probs,
    int* __restrict__ idxArr, float* __restrict__ lossOut)
{
  const int m0 = blockIdx.x * 64;
  const int g  = blockIdx.y;
  const int b  = m0 / T_;
  const int t  = threadIdx.x;
  const int tx = t & 31, ty = t >> 5;

  __shared__ float As[256][68];   // [ch][tok] 69,632 B
  __shared__ float Bs[32][321];   // [ch-slice][code] 41,088 B
  __shared__ float qT[K_];
  __shared__ float zn2[64];

  const float mean = meanArr[b * G_ + g];
  const float rstd = rstdArr[b * G_ + g];

  // stage A (normalized) + znorm2 per token; thread t -> token t>>2, ch quarter
  {
    const int tok = t >> 2;
    const int c0 = (t & 3) * 64;
    const float* src = &Ze[(size_t)(m0 + tok) * Dc_ + g * Cg_ + c0];
    float part = 0.f;
    #pragma unroll
    for (int i = 0; i < 16; ++i) {
      float4 v  = *(const float4*)&src[i * 4];
      float4 w4 = *(const float4*)&gnw[g * Cg_ + c0 + i * 4];
      float4 b4 = *(const float4*)&gnb[g * Cg_ + c0 + i * 4];
      float z0 = (v.x - mean) * rstd * w4.x + b4.x;
      float z1 = (v.y - mean) * rstd * w4.y + b4.y;
      float z2 = (v.z - mean) * rstd * w4.z + b4.z;
      float z3 = (v.w - mean) * rstd * w4.w + b4.w;
      As[c0 + i*4 + 0][tok] = z0; As[c0 + i*4 + 1][tok] = z1;
      As[c0 + i*4 + 2][tok] = z2; As[c0 + i*4 + 3][tok] = z3;
      part += z0*z0 + z1*z1 + z2*z2 + z3*z3;
    }
    part += __shfl_down(part, 1);
    part += __shfl_down(part, 2);
    if ((t & 3) == 0) zn2[tok] = part;
  }
  qT[t] = qArr[g * K_ + t];
  if (t < 64) qT[256 + t] = qArr[g * K_ + 256 + t];

  float acc[8][10];
  #pragma unroll
  for (int i = 0; i < 8; ++i)
    #pragma unroll
    for (int j = 0; j < 10; ++j) acc[i][j] = 0.f;

  for (int k0 = 0; k0 < Cg_; k0 += 32) {
    #pragma unroll
    for (int i = 0; i < 10; ++i) {
      int f = t + 256 * i;            // 0..2559
      int code = f >> 3, cq = f & 7;  // 320 codes x 8 float4
      float4 v = *(const float4*)&codex[((size_t)(g * K_ + code)) * Cg_ + k0 + cq * 4];
      int kk = cq * 4;
      Bs[kk+0][code] = v.x; Bs[kk+1][code] = v.y;
      Bs[kk+2][code] = v.z; Bs[kk+3][code] = v.w;
    }
    __syncthreads();
    #pragma unroll 8
    for (int kk = 0; kk < 32; ++kk) {
      float av[8];
      *(float4*)&av[0] = *(const float4*)&As[k0 + kk][ty * 4];
      *(float4*)&av[4] = *(const float4*)&As[k0 + kk][32 + ty * 4];
      float bv[10];
      #pragma unroll
      for (int j = 0; j < 10; ++j) bv[j] = Bs[kk][tx + 32 * j];
      #pragma unroll
      for (int i = 0; i < 8; ++i)
        #pragma unroll
        for (int j = 0; j < 10; ++j)
          acc[i][j] = fmaf(av[i], bv[j], acc[i][j]);
    }
    __syncthreads();
  }

  // argmin epilogue; scratch overlays Bs (no longer read)
  float* scratch = &Bs[0][0];
  float* mval = scratch;                 // [64][32]
  int*   midx = (int*)(scratch + 2048);  // [64][32]

  #pragma unroll
  for (int i = 0; i < 8; ++i) {
    const int tok = (i < 4) ? (ty * 4 + i) : (32 + ty * 4 + (i - 4));
    const float znv = zn2[tok];
    float best = INFINITY; int bi = 0x7fffffff;
    #pragma unroll
    for (int j = 0; j < 10; ++j) {
      int k = tx + 32 * j;
      // faithful to reference: fl(zn2 + cn2) - fl(2*dot), no contraction
      float t1 = __fadd_rn(znv, qT[k]);
      float d  = __fsub_rn(t1, __fmul_rn(2.0f, acc[i][j]));
      if (d < best) { best = d; bi = k; }  // j ascending => first-index ties ok
    }
    mval[tok * 32 + tx] = best;
    midx[tok * 32 + tx] = bi;
  }
  __syncthreads();

  if (t < 64) {
    const int tok = t;
    float best = INFINITY; int bi = 0x7fffffff;
    for (int j = 0; j < 32; ++j) {
      float v = mval[tok * 32 + j];
      int  ii = midx[tok * 32 + j];
      if (v < best || (v == best && ii < bi)) { best = v; bi = ii; }
    }
    const int n = m0 + tok;
    idxArr[n * 2 + g] = bi;
    probs[((size_t)n * G_ + g) * K_ + bi] = 1.0f;
    // loss partial: sum of best distances across this wave (t<64 == wave 0)
    float bl = best;
    #pragma unroll
    for (int off = 32; off; off >>= 1) bl += __shfl_down(bl, off);
    if (t == 0)
      atomicAdd(lossOut, bl * (1.25f / (float)((size_t)N_ * G_ * Cg_)));
  }
}

// ----------------------------------------------------------------- k_out ----
// out[n,d] = r*(U0[i0,d]+U1[i1,d]) - r*m*WL[d] + CC[d]
__global__ __launch_bounds__(256) void k_out(
    const int* __restrict__ idxArr, const float* __restrict__ U,
    const float* __restrict__ WL, const float* __restrict__ CC,
    const float* __restrict__ sArr, const float* __restrict__ qArr,
    float* __restrict__ out)
{
  const int n = blockIdx.x;
  const int t = threadIdx.x;
  __shared__ float sh[2];
  __shared__ int   shi[2];
  if (t == 0) {
    int i0 = idxArr[n * 2 + 0], i1 = idxArr[n * 2 + 1];
    float m   = (sArr[i0] + sArr[K_ + i1]) * (1.0f / Dc_);
    float var = (qArr[i0] + qArr[K_ + i1]) * (1.0f / Dc_) - m * m;
    float r = rsqrtf(var + EPS_LN);
    sh[0] = r; sh[1] = r * m;
    shi[0] = i0; shi[1] = i1;
  }
  __syncthreads();
  const float r = sh[0], rm = sh[1];
  const float* u0 = &U[(size_t)shi[0] * D_];
  const float* u1 = &U[(size_t)(K_ + shi[1]) * D_];
  const int d = t * 4;
  float4 a = *(const float4*)&u0[d];
  float4 b = *(const float4*)&u1[d];
  float4 w = *(const float4*)&WL[d];
  float4 c = *(const float4*)&CC[d];
  float4 o;
  o.x = r * (a.x + b.x) - rm * w.x + c.x;
  o.y = r * (a.y + b.y) - rm * w.y + c.y;
  o.z = r * (a.z + b.z) - rm * w.z + c.z;
  o.w = r * (a.w + b.w) - rm * w.w + c.w;
  *(float4*)&out[(size_t)n * D_ + d] = o;
}

// ---------------------------------------------------------------------------
extern "C" void kernel_launch(void* const* d_in, const int* in_sizes, int n_in,
                              void* d_out, int out_size, void* d_ws, size_t ws_size,
                              hipStream_t stream)
{
  const float* Z      = (const float*)d_in[0];
  const float* conv_w = (const float*)d_in[1];
  const float* gnw    = (const float*)d_in[2];
  const float* gnb    = (const float*)d_in[3];
  const float* codex  = (const float*)d_in[4];
  const float* lnw    = (const float*)d_in[5];
  const float* lnb    = (const float*)d_in[6];
  const float* pw     = (const float*)d_in[7];
  const float* pb     = (const float*)d_in[8];

  float* out     = (float*)d_out;
  float* lossOut = out + (size_t)N_ * D_;   // 1 element
  float* probs   = lossOut + 1;             // N*G*K one-hot

  char* w = (char*)d_ws;
  float* Ze        = (float*)w; w += (size_t)N_ * Dc_ * 4;
  float* U         = (float*)w; w += (size_t)G_ * K_ * D_ * 4;
  float* WL        = (float*)w; w += D_ * 4;
  float* CC        = (float*)w; w += D_ * 4;
  float* sArr      = (float*)w; w += G_ * K_ * 4;
  float* qArr      = (float*)w; w += G_ * K_ * 4;
  double* statsSum = (double*)w; w += B_ * G_ * 2 * 8;
  float* meanArr   = (float*)w; w += B_ * G_ * 4;
  float* rstdArr   = (float*)w; w += B_ * G_ * 4;
  int*  idxArr     = (int*)w;  w += (size_t)N_ * 2 * 4;

  if ((size_t)(w - (char*)d_ws) > ws_size) return;  // ws too small: bail clean

  // zero loss + one-hot probs region of d_out, and the stats accumulators
  hipMemsetAsync(lossOut, 0, (size_t)(1 + (size_t)N_ * G_ * K_) * 4, stream);
  hipMemsetAsync(statsSum, 0, (size_t)B_ * G_ * 2 * 8, stream);

  k_prep <<<G_ * K_ + 2, 256, 0, stream>>>(codex, lnw, lnb, pw, pb,
                                           U, WL, CC, sArr, qArr);
  k_conv <<<dim3(N_ / 128, 2, G_), 256, 0, stream>>>(Z, conv_w, Ze, statsSum);
  k_stats<<<1, 64, 0, stream>>>(statsSum, meanArr, rstdArr);
  k_dist <<<dim3(N_ / 64, G_), 256, 0, stream>>>(Ze, codex, gnw, gnb,
                                                 meanArr, rstdArr, qArr,
                                                 probs, idxArr, lossOut);
  k_out  <<<N_, 256, 0, stream>>>(idxArr, U, WL, CC, sArr, qArr, out);
}

// Round 8
// 1461.772 us; speedup vs baseline: 1.1465x; 1.1465x over previous
//
#include <hip/hip_runtime.h>
#include <math.h>

// ---------------------------------------------------------------------------
// KmeansVectorQuantizer forward, MI355X fp32 implementation.
//
// Pipeline:
//   k_prep  : per-codeword tables  U[g][k][d] = sum_c codex[g,k,c]*lnw[c']*pw[d,c']
//             + WL[d] = sum_c lnw*pw, CC[d] = sum_c lnb*pw + pb
//             + s[gk] = sum codex, q[gk] = sum codex^2 (q == cnorm2)
//   k_conv  : grouped 1x1 conv as fp32 VALU GEMM (128x128 tile, 8x8 micro),
//             fused fp64 GroupNorm sum/sumsq atomics per (b,g)
//   k_stats : finalize mean/rstd per (b,g)
//   k_dist  : normalize Ze -> Zn on the fly (K-sliced LDS staging), fp32 GEMM
//             vs codex (64 tok x 320 codes, 8x10 micro), faithful
//             dist = fl(zn2+cn2) - fl(2*dot), argmin (first-index ties),
//             writes probs one-hot, idx, loss atomic
//   k_out   : out[n] = r*(U0[i0]+U1[i1]) - r*m*WL + CC   (table-based LN+Linear)
//
// R5 -> R6: k_dist LDS 112.6KB -> 51.3KB (K-sliced As) for 1 -> 3 blocks/CU.
//   R5 counters: Occupancy 10.9% (1 blk/CU), VALUBusy 43.6%, dur 586us.
// ---------------------------------------------------------------------------

#define B_   16
#define T_   4096
#define D_   1024
#define G_   2
#define Cg_  256
#define Dc_  512
#define K_   320
#define N_   (B_*T_)            // 65536 tokens
#define GNM  ((double)(T_*Cg_)) // elements per (b,g) group-norm
#define EPS_GN 1e-5f
#define EPS_LN 1e-5f

// ---------------------------------------------------------------- k_prep ----
__global__ __launch_bounds__(256) void k_prep(
    const float* __restrict__ codex, const float* __restrict__ lnw,
    const float* __restrict__ lnb,   const float* __restrict__ pw,
    const float* __restrict__ pb,
    float* __restrict__ U, float* __restrict__ WL, float* __restrict__ CC,
    float* __restrict__ sArr, float* __restrict__ qArr)
{
  __shared__ float arow[512];
  __shared__ float reds[8];
  const int blk = blockIdx.x;
  const int t = threadIdx.x;
  const int lane = t & 63, wave = t >> 6;

  if (blk < G_ * K_) {
    const int g = blk / K_;
    // stage arow[c] = codex[g][k][c] * lnw[g*256+c]; reduce s, q
    float cv = codex[(size_t)blk * Cg_ + t];
    float lw = lnw[g * Cg_ + t];
    arow[t] = cv * lw;
    float s = cv, q = cv * cv;
    #pragma unroll
    for (int off = 32; off; off >>= 1) {
      s += __shfl_down(s, off);
      q += __shfl_down(q, off);
    }
    if (lane == 0) { reds[wave] = s; reds[4 + wave] = q; }
    __syncthreads();
    if (t == 0) {
      sArr[blk] = reds[0] + reds[1] + reds[2] + reds[3];
      qArr[blk] = reds[4] + reds[5] + reds[6] + reds[7];
    }
    // U rows: one wave per output row d
    const float* pwg = pw + g * Cg_;
    for (int r = wave; r < D_; r += 4) {
      float4 pv = *(const float4*)&pwg[(size_t)r * Dc_ + lane * 4];
      float4 av = *(const float4*)&arow[lane * 4];
      float dot = pv.x*av.x + pv.y*av.y + pv.z*av.z + pv.w*av.w;
      #pragma unroll
      for (int off = 32; off; off >>= 1) dot += __shfl_down(dot, off);
      if (lane == 0) U[(size_t)blk * D_ + r] = dot;
    }
  } else {
    const bool isCC = (blk == G_ * K_ + 1);
    const float* src = isCC ? lnb : lnw;
    arow[t] = src[t];
    arow[256 + t] = src[256 + t];
    __syncthreads();
    for (int r = wave; r < D_; r += 4) {
      const float* prow = &pw[(size_t)r * Dc_];
      float4 p0 = *(const float4*)&prow[lane * 4];
      float4 p1 = *(const float4*)&prow[256 + lane * 4];
      float4 a0 = *(const float4*)&arow[lane * 4];
      float4 a1 = *(const float4*)&arow[256 + lane * 4];
      float dot = p0.x*a0.x + p0.y*a0.y + p0.z*a0.z + p0.w*a0.w
                + p1.x*a1.x + p1.y*a1.y + p1.z*a1.z + p1.w*a1.w;
      #pragma unroll
      for (int off = 32; off; off >>= 1) dot += __shfl_down(dot, off);
      if (lane == 0) {
        if (isCC) CC[r] = dot + pb[r]; else WL[r] = dot;
      }
    }
  }
}

// ---------------------------------------------------------------- k_conv ----
// C[m, n] = sum_k Z[m, g*512+k] * W[g, n, k]   (m: token, n: out-channel)
// Tile 128x128, BK=32, 256 threads, 8x8 micro-tile (rows {4ty..}+{64+4ty..}).
__global__ __launch_bounds__(256, 2) void k_conv(
    const float* __restrict__ Z, const float* __restrict__ W,
    float* __restrict__ Ze, double* __restrict__ statsSum)
{
  const int m0 = blockIdx.x * 128;
  const int n0 = blockIdx.y * 128;
  const int g  = blockIdx.z;
  const int t  = threadIdx.x;
  const int tx = t & 15, ty = t >> 4;
  const int lane = t & 63, wave = t >> 6;

  __shared__ float As[32][132];  // [k][m], stride 132 (16B aligned, bank-safe)
  __shared__ float Bs[32][132];  // [k][n]
  __shared__ double redC[8];

  float acc[8][8];
  #pragma unroll
  for (int i = 0; i < 8; ++i)
    #pragma unroll
    for (int j = 0; j < 8; ++j) acc[i][j] = 0.f;

  const float* Ag = Z + (size_t)m0 * D_ + g * 512;
  const float* Bg = W + ((size_t)g * Cg_ + n0) * 512;

  for (int k0 = 0; k0 < 512; k0 += 32) {
    #pragma unroll
    for (int i = 0; i < 4; ++i) {
      int f = t + 256 * i;          // 0..1023
      int row = f >> 3, cq = f & 7; // row 0..127, 8 float4 per row of 32 k
      float4 a = *(const float4*)&Ag[(size_t)row * D_ + k0 + cq * 4];
      int kk = cq * 4;
      As[kk+0][row] = a.x; As[kk+1][row] = a.y;
      As[kk+2][row] = a.z; As[kk+3][row] = a.w;
      float4 b = *(const float4*)&Bg[(size_t)row * 512 + k0 + cq * 4];
      Bs[kk+0][row] = b.x; Bs[kk+1][row] = b.y;
      Bs[kk+2][row] = b.z; Bs[kk+3][row] = b.w;
    }
    __syncthreads();
    #pragma unroll 8
    for (int kk = 0; kk < 32; ++kk) {
      float av[8], bv[8];
      *(float4*)&av[0] = *(const float4*)&As[kk][ty * 4];
      *(float4*)&av[4] = *(const float4*)&As[kk][64 + ty * 4];
      *(float4*)&bv[0] = *(const float4*)&Bs[kk][tx * 4];
      *(float4*)&bv[4] = *(const float4*)&Bs[kk][64 + tx * 4];
      #pragma unroll
      for (int i = 0; i < 8; ++i)
        #pragma unroll
        for (int j = 0; j < 8; ++j)
          acc[i][j] = fmaf(av[i], bv[j], acc[i][j]);
    }
    __syncthreads();
  }

  // write C + fused GroupNorm partial sums (fp64)
  double bs = 0.0, bq = 0.0;
  #pragma unroll
  for (int i = 0; i < 8; ++i) {
    int m = m0 + ((i < 4) ? (ty * 4 + i) : (64 + ty * 4 + (i - 4)));
    float4 c0, c1;
    c0.x = acc[i][0]; c0.y = acc[i][1]; c0.z = acc[i][2]; c0.w = acc[i][3];
    c1.x = acc[i][4]; c1.y = acc[i][5]; c1.z = acc[i][6]; c1.w = acc[i][7];
    *(float4*)&Ze[(size_t)m * Dc_ + g * Cg_ + n0 + tx * 4] = c0;
    *(float4*)&Ze[(size_t)m * Dc_ + g * Cg_ + n0 + 64 + tx * 4] = c1;
    #pragma unroll
    for (int j = 0; j < 8; ++j) {
      double v = (double)acc[i][j];
      bs += v; bq += v * v;
    }
  }
  #pragma unroll
  for (int off = 32; off; off >>= 1) {
    bs += __shfl_down(bs, off);
    bq += __shfl_down(bq, off);
  }
  if (lane == 0) { redC[wave] = bs; redC[4 + wave] = bq; }
  __syncthreads();
  if (t == 0) {
    const int b = m0 / T_;
    atomicAdd(&statsSum[(b * G_ + g) * 2 + 0], redC[0]+redC[1]+redC[2]+redC[3]);
    atomicAdd(&statsSum[(b * G_ + g) * 2 + 1], redC[4]+redC[5]+redC[6]+redC[7]);
  }
}

// --------------------------------------------------------------- k_stats ----
__global__ void k_stats(const double* __restrict__ statsSum,
                        float* __restrict__ meanArr, float* __restrict__ rstdArr)
{
  int i = threadIdx.x;
  if (i < B_ * G_) {
    double s = statsSum[i * 2 + 0], q = statsSum[i * 2 + 1];
    double mean = s / GNM;
    double var = q / GNM - mean * mean;
    meanArr[i] = (float)mean;
    rstdArr[i] = (float)(1.0 / sqrt(var + (double)EPS_GN));
  }
}

// ---------------------------------------------------------------- k_dist ----
// Per (64-token block, g): K-sliced staging — As holds one 32-channel slice
// of the normalized A tile (8.7KB) instead of all 256 channels (69.6KB).
// zn2 partials accumulate in registers across slices. LDS total ~51.3KB
// -> 3 blocks/CU (was 1). 8 tok x 10 code micro-tile per thread.
__global__ __launch_bounds__(256) void k_dist(
    const float* __restrict__ Ze, const float* __restrict__ codex,
    const float* __restrict__ gnw, const float* __restrict__ gnb,
    const float* __restrict__ meanArr, const float* __restrict__ rstdArr,
    const float* __restrict__ qArr, float* __restrict__ probs,
    int* __restrict__ idxArr, float* __restrict__ lossOut)
{
  const int m0 = blockIdx.x * 64;
  const int g  = blockIdx.y;
  const int b  = m0 / T_;
  const int t  = threadIdx.x;
  const int tx = t & 31, ty = t >> 5;

  __shared__ float As[32][68];    // [ch-slice][tok]  8,704 B
  __shared__ float Bs[32][321];   // [ch-slice][code] 41,088 B
  __shared__ float qT[K_];
  __shared__ float zn2[64];

  const float mean = meanArr[b * G_ + g];
  const float rstd = rstdArr[b * G_ + g];

  qT[t] = qArr[g * K_ + t];
  if (t < 64) qT[256 + t] = qArr[g * K_ + 256 + t];

  float acc[8][10];
  #pragma unroll
  for (int i = 0; i < 8; ++i)
    #pragma unroll
    for (int j = 0; j < 10; ++j) acc[i][j] = 0.f;

  const int tokS = t >> 2;        // staging token (16 tokens per lane-quad set)
  const int cS   = (t & 3) * 8;   // staging channel base within 32-slice
  float part = 0.f;               // zn2 partial (this thread's channels)

  for (int k0 = 0; k0 < Cg_; k0 += 32) {
    // stage A slice (normalized on the fly) + zn2 partial accumulation
    {
      const float* src  = &Ze[(size_t)(m0 + tokS) * Dc_ + g * Cg_ + k0 + cS];
      const float* wsrc = &gnw[g * Cg_ + k0 + cS];
      const float* bsrc = &gnb[g * Cg_ + k0 + cS];
      #pragma unroll
      for (int h = 0; h < 2; ++h) {
        float4 v  = *(const float4*)&src[h * 4];
        float4 w4 = *(const float4*)&wsrc[h * 4];
        float4 b4 = *(const float4*)&bsrc[h * 4];
        float z0 = (v.x - mean) * rstd * w4.x + b4.x;
        float z1 = (v.y - mean) * rstd * w4.y + b4.y;
        float z2 = (v.z - mean) * rstd * w4.z + b4.z;
        float z3 = (v.w - mean) * rstd * w4.w + b4.w;
        As[cS + h*4 + 0][tokS] = z0; As[cS + h*4 + 1][tokS] = z1;
        As[cS + h*4 + 2][tokS] = z2; As[cS + h*4 + 3][tokS] = z3;
        part += z0*z0 + z1*z1 + z2*z2 + z3*z3;
      }
    }
    // stage B slice
    #pragma unroll
    for (int i = 0; i < 10; ++i) {
      int f = t + 256 * i;            // 0..2559
      int code = f >> 3, cq = f & 7;  // 320 codes x 8 float4
      float4 v = *(const float4*)&codex[((size_t)(g * K_ + code)) * Cg_ + k0 + cq * 4];
      int kk = cq * 4;
      Bs[kk+0][code] = v.x; Bs[kk+1][code] = v.y;
      Bs[kk+2][code] = v.z; Bs[kk+3][code] = v.w;
    }
    __syncthreads();
    #pragma unroll 8
    for (int kk = 0; kk < 32; ++kk) {
      float av[8];
      *(float4*)&av[0] = *(const float4*)&As[kk][ty * 4];
      *(float4*)&av[4] = *(const float4*)&As[kk][32 + ty * 4];
      float bv[10];
      #pragma unroll
      for (int j = 0; j < 10; ++j) bv[j] = Bs[kk][tx + 32 * j];
      #pragma unroll
      for (int i = 0; i < 8; ++i)
        #pragma unroll
        for (int j = 0; j < 10; ++j)
          acc[i][j] = fmaf(av[i], bv[j], acc[i][j]);
    }
    __syncthreads();
  }

  // finalize zn2: reduce the 4 lanes sharing each token
  part += __shfl_down(part, 1);
  part += __shfl_down(part, 2);
  if ((t & 3) == 0) zn2[tokS] = part;
  __syncthreads();

  // argmin epilogue; scratch overlays Bs (no longer read)
  float* scratch = &Bs[0][0];
  float* mval = scratch;                 // [64][32]
  int*   midx = (int*)(scratch + 2048);  // [64][32]

  #pragma unroll
  for (int i = 0; i < 8; ++i) {
    const int tok = (i < 4) ? (ty * 4 + i) : (32 + ty * 4 + (i - 4));
    const float znv = zn2[tok];
    float best = INFINITY; int bi = 0x7fffffff;
    #pragma unroll
    for (int j = 0; j < 10; ++j) {
      int k = tx + 32 * j;
      // faithful to reference: fl(zn2 + cn2) - fl(2*dot), no contraction
      float t1 = __fadd_rn(znv, qT[k]);
      float d  = __fsub_rn(t1, __fmul_rn(2.0f, acc[i][j]));
      if (d < best) { best = d; bi = k; }  // j ascending => first-index ties ok
    }
    mval[tok * 32 + tx] = best;
    midx[tok * 32 + tx] = bi;
  }
  __syncthreads();

  if (t < 64) {
    const int tok = t;
    float best = INFINITY; int bi = 0x7fffffff;
    for (int j = 0; j < 32; ++j) {
      float v = mval[tok * 32 + j];
      int  ii = midx[tok * 32 + j];
      if (v < best || (v == best && ii < bi)) { best = v; bi = ii; }
    }
    const int n = m0 + tok;
    idxArr[n * 2 + g] = bi;
    probs[((size_t)n * G_ + g) * K_ + bi] = 1.0f;
    // loss partial: sum of best distances across this wave (t<64 == wave 0)
    float bl = best;
    #pragma unroll
    for (int off = 32; off; off >>= 1) bl += __shfl_down(bl, off);
    if (t == 0)
      atomicAdd(lossOut, bl * (1.25f / (float)((size_t)N_ * G_ * Cg_)));
  }
}

// ----------------------------------------------------------------- k_out ----
// out[n,d] = r*(U0[i0,d]+U1[i1,d]) - r*m*WL[d] + CC[d]
__global__ __launch_bounds__(256) void k_out(
    const int* __restrict__ idxArr, const float* __restrict__ U,
    const float* __restrict__ WL, const float* __restrict__ CC,
    const float* __restrict__ sArr, const float* __restrict__ qArr,
    float* __restrict__ out)
{
  const int n = blockIdx.x;
  const int t = threadIdx.x;
  __shared__ float sh[2];
  __shared__ int   shi[2];
  if (t == 0) {
    int i0 = idxArr[n * 2 + 0], i1 = idxArr[n * 2 + 1];
    float m   = (sArr[i0] + sArr[K_ + i1]) * (1.0f / Dc_);
    float var = (qArr[i0] + qArr[K_ + i1]) * (1.0f / Dc_) - m * m;
    float r = rsqrtf(var + EPS_LN);
    sh[0] = r; sh[1] = r * m;
    shi[0] = i0; shi[1] = i1;
  }
  __syncthreads();
  const float r = sh[0], rm = sh[1];
  const float* u0 = &U[(size_t)shi[0] * D_];
  const float* u1 = &U[(size_t)(K_ + shi[1]) * D_];
  const int d = t * 4;
  float4 a = *(const float4*)&u0[d];
  float4 b = *(const float4*)&u1[d];
  float4 w = *(const float4*)&WL[d];
  float4 c = *(const float4*)&CC[d];
  float4 o;
  o.x = r * (a.x + b.x) - rm * w.x + c.x;
  o.y = r * (a.y + b.y) - rm * w.y + c.y;
  o.z = r * (a.z + b.z) - rm * w.z + c.z;
  o.w = r * (a.w + b.w) - rm * w.w + c.w;
  *(float4*)&out[(size_t)n * D_ + d] = o;
}

// ---------------------------------------------------------------------------
extern "C" void kernel_launch(void* const* d_in, const int* in_sizes, int n_in,
                              void* d_out, int out_size, void* d_ws, size_t ws_size,
                              hipStream_t stream)
{
  const float* Z      = (const float*)d_in[0];
  const float* conv_w = (const float*)d_in[1];
  const float* gnw    = (const float*)d_in[2];
  const float* gnb    = (const float*)d_in[3];
  const float* codex  = (const float*)d_in[4];
  const float* lnw    = (const float*)d_in[5];
  const float* lnb    = (const float*)d_in[6];
  const float* pw     = (const float*)d_in[7];
  const float* pb     = (const float*)d_in[8];

  float* out     = (float*)d_out;
  float* lossOut = out + (size_t)N_ * D_;   // 1 element
  float* probs   = lossOut + 1;             // N*G*K one-hot

  char* w = (char*)d_ws;
  float* Ze        = (float*)w; w += (size_t)N_ * Dc_ * 4;
  float* U         = (float*)w; w += (size_t)G_ * K_ * D_ * 4;
  float* WL        = (float*)w; w += D_ * 4;
  float* CC        = (float*)w; w += D_ * 4;
  float* sArr      = (float*)w; w += G_ * K_ * 4;
  float* qArr      = (float*)w; w += G_ * K_ * 4;
  double* statsSum = (double*)w; w += B_ * G_ * 2 * 8;
  float* meanArr   = (float*)w; w += B_ * G_ * 4;
  float* rstdArr   = (float*)w; w += B_ * G_ * 4;
  int*  idxArr     = (int*)w;  w += (size_t)N_ * 2 * 4;

  if ((size_t)(w - (char*)d_ws) > ws_size) return;  // ws too small: bail clean

  // zero loss + one-hot probs region of d_out, and the stats accumulators
  hipMemsetAsync(lossOut, 0, (size_t)(1 + (size_t)N_ * G_ * K_) * 4, stream);
  hipMemsetAsync(statsSum, 0, (size_t)B_ * G_ * 2 * 8, stream);

  k_prep <<<G_ * K_ + 2, 256, 0, stream>>>(codex, lnw, lnb, pw, pb,
                                           U, WL, CC, sArr, qArr);
  k_conv <<<dim3(N_ / 128, 2, G_), 256, 0, stream>>>(Z, conv_w, Ze, statsSum);
  k_stats<<<1, 64, 0, stream>>>(statsSum, meanArr, rstdArr);
  k_dist <<<dim3(N_ / 64, G_), 256, 0, stream>>>(Ze, codex, gnw, gnb,
                                                 meanArr, rstdArr, qArr,
                                                 probs, idxArr, lossOut);
  k_out  <<<N_, 256, 0, stream>>>(idxArr, U, WL, CC, sArr, qArr, out);
}